// Round 9
// baseline (842.429 us; speedup 1.0000x reference)
//
#include <hip/hip_runtime.h>

// LSTM decoder: B=256, H=512, L=2, T=64, O=7
// Round 16 = r14 banked baseline (821.9us, PASS) + direct f32 weight-fragment
// loads in lstm_persist:
//  - prologue's 2048-block Wc conversion (16MB read + 8MB write) DELETED;
//    lstm loads its own 64 Bw fragment-rows straight from Wih/Whh (f32) and
//    converts inline with the same (h16) casts -> bit-identical Bw, output.
//  - phase loop / flag protocol / epilogue: byte-identical to r14 (proven).
//    Six phase-loop restructurings failed (suspected spill-before-load-return
//    corruption of asm-staged tmp under raised VGPR pressure); frozen.
//  - prologue now 1680 blocks: [0,1552) x/h0 inits + bias, [1552,1680) flags.

#define TT 64
#define NO 7

typedef _Float16 h16;
typedef __attribute__((ext_vector_type(8))) _Float16 half8;
typedef __attribute__((ext_vector_type(4))) float f32x4;
typedef __attribute__((ext_vector_type(4))) int i32x4;

__device__ __forceinline__ float sigf(float x)   { return 1.f / (1.f + __expf(-x)); }
__device__ __forceinline__ float tanhf_(float x) { return 1.f - 2.f / (__expf(2.f * x) + 1.f); }

// convert 8 consecutive f32 -> half8 (same casts as the old prep_weights)
__device__ __forceinline__ half8 cvt8(const float* p) {
    float4 a = ((const float4*)p)[0];
    float4 b = ((const float4*)p)[1];
    half8 o;
    o[0] = (h16)a.x; o[1] = (h16)a.y; o[2] = (h16)a.z; o[3] = (h16)a.w;
    o[4] = (h16)b.x; o[5] = (h16)b.y; o[6] = (h16)b.z; o[7] = (h16)b.w;
    return o;
}

// ---------------- prologue: inits + bias + flag zero ------------------------
// blocks [0,1552): Xinit/H0init/H1init + bias; blocks [1552,1680): flags zero
__global__ __launch_bounds__(256) void prologue(
    const float* __restrict__ x, const float* __restrict__ h0,
    const float* __restrict__ bih, const float* __restrict__ bhh,
    h16* __restrict__ Xinit, h16* __restrict__ H0init, h16* __restrict__ H1init,
    float* __restrict__ bias, unsigned* __restrict__ flags)
{
    int blk = blockIdx.x;
    if (blk < 1552) {
        int i = blk * 256 + threadIdx.x;
        if (i < 131072) { Xinit[i]  = (h16)x[i];           return; }
        i -= 131072;
        if (i < 131072) { H0init[i] = (h16)h0[i];          return; }
        i -= 131072;
        if (i < 131072) { H1init[i] = (h16)h0[131072 + i]; return; }
        i -= 131072;
        if (i < 4096) bias[i] = bih[i] + bhh[i];
        return;
    }
    blk -= 1552;
    // flags zero: 128 blocks x 256 threads x 16B = 512KB
    i32x4 z = {0, 0, 0, 0};
    *(i32x4*)(flags + (size_t)(blk * 256 + threadIdx.x) * 4) = z;
}

// ---------------- persistent LSTM (r14 loop body, verbatim) ------------------
// 256 WGs x 256 thr, 1 WG/CU. XCD-pinned: m = (wg&7)>>1, us = (wg>>3)+(wg&1)*32.
// WG: 64-row m-tile x 8 h-units. Wave w: rows (w>>1)*32..+32, units (w&1)*4..+4
// (16 gate-cols, col = 4*ulocal + gate).
__global__ __launch_bounds__(256, 1) void lstm_persist(
    const float* __restrict__ Wih, const float* __restrict__ Whh,
    const float* __restrict__ bias,
    const float* __restrict__ c0in,
    const h16* __restrict__ Xinit, const h16* __restrict__ H0init,
    const h16* __restrict__ H1init,
    h16* __restrict__ H0, h16* __restrict__ H1,
    float* __restrict__ h_st, float* __restrict__ c_st,
    unsigned* __restrict__ flags)
{
    __shared__ char ldsraw[65536];   // 2 x 32KB A-chunk double buffer

    const int wg   = blockIdx.x;
    const int m    = (wg & 7) >> 1;               // XCD-pinned m-group
    const int us   = (wg >> 3) + (wg & 1) * 32;   // unit slice 0..63
    const int myoct = us >> 3;
    const int tid  = threadIdx.x, w = tid >> 6, lane = tid & 63;
    const int u0   = us * 8;
    const int m0   = m * 64;
    const int rowbase = m0 + (w >> 1) * 32;
    const int ubase   = u0 + (w & 1) * 4;
    const int mcol = lane & 15, kq = lane >> 4;
    const int nrow = (mcol & 3) * 512 + ubase + (mcol >> 2);
    const int lrow = (w >> 1) * 32 + mcol;     // local row of m-subtile 0
    const int sw   = mcol & 7;                 // LDS XOR swizzle key
    const int lrloc = (w >> 1) * 32 + (lane >> 2);   // epilogue local row
    const int luloc = (w & 1) * 4 + (lane & 3);      // epilogue local unit

    // ---- B fragments for both layers, DIRECT from f32 weights (bit-identical
    //      to the old Wc path: same element order, same (h16) casts) ----
    // Bw[l][ks][e] = Wc[l][nrow][ks*32 + kq*8 + e]:
    //   ks<16 -> Wih[l][nrow][ks*32+kq*8+e], ks>=16 -> Whh[l][nrow][(ks-16)*32+kq*8+e]
    half8 Bw0[32], Bw1[32];
    {
        const float* wih0 = Wih + (size_t)nrow * 512 + kq * 8;
        const float* whh0 = Whh + (size_t)nrow * 512 + kq * 8;
        const float* wih1 = Wih + (size_t)(2048 + nrow) * 512 + kq * 8;
        const float* whh1 = Whh + (size_t)(2048 + nrow) * 512 + kq * 8;
#pragma unroll
        for (int ks = 0; ks < 16; ++ks) {
            Bw0[ks]      = cvt8(wih0 + ks * 32);
            Bw0[16 + ks] = cvt8(whh0 + ks * 32);
            Bw1[ks]      = cvt8(wih1 + ks * 32);
            Bw1[16 + ks] = cvt8(whh1 + ks * 32);
        }
    }

    // ---- epilogue lane mapping (round-2/5/6 verified) ----
    const int eunit = ubase + (lane & 3);
    const int erow0 = rowbase + (lane >> 2);   // m-subtile 0; +16 for subtile 1
    float4 bz0 = make_float4(bias[eunit], bias[512 + eunit],
                             bias[1024 + eunit], bias[1536 + eunit]);
    float4 bz1 = make_float4(bias[2048 + eunit], bias[2048 + 512 + eunit],
                             bias[2048 + 1024 + eunit], bias[2048 + 1536 + eunit]);

    float creg[2][2], hreg[2][2];
#pragma unroll
    for (int mt = 0; mt < 2; ++mt) {
        creg[0][mt] = c0in[(erow0 + mt * 16) * 512 + eunit];
        creg[1][mt] = c0in[131072 + (erow0 + mt * 16) * 512 + eunit];
        hreg[0][mt] = 0.f; hreg[1][mt] = 0.f;
    }

// plain CACHED 16B loads of k-half `cs` (0/1) of the 64-row tile at BASE
// (row stride 1024B) into tmp[TB..TB+7]. Issue order defines vmcnt drains.
#define ISSUE_CHUNK(BASE, cs, TB) do {                                        \
    _Pragma("unroll")                                                         \
    for (int j = 0; j < 8; ++j) {                                             \
        int g = j * 256 + tid;                                                \
        int voff = (g >> 5) * 1024 + (cs) * 512 + (g & 31) * 16;              \
        asm volatile("global_load_dwordx4 %0, %1, %2"                         \
            : "=v"(tmp[(TB) + j]) : "v"(voff), "s"(BASE) : "memory");         \
    } } while (0)

// drain 8 loads (oldest-first) into LDS buffer `par` with XOR swizzle.
// NB = (outstanding when entering) - 1.
#define WRITE_CHUNK(par, TB, NB) do {                                         \
    _Pragma("unroll")                                                         \
    for (int j = 0; j < 8; ++j) {                                             \
        asm volatile("s_waitcnt vmcnt(%0)" :: "i"((NB) - j) : "memory");      \
        int g = j * 256 + tid;                                                \
        int row = g >> 5, bc = g & 31;                                        \
        *(i32x4*)(ldsraw + (par) * 32768 + row * 512 +                        \
                  ((bc ^ (row & 7)) * 16)) = tmp[(TB) + j];                   \
    } } while (0)

// 8 k-steps of MFMA from LDS buffer `par` against B fragments BW[CO..CO+7]
#define MFMA_CHUNK(par, CO, BW) do {                                          \
    _Pragma("unroll")                                                         \
    for (int ks = 0; ks < 8; ++ks) {                                          \
        half8 a0 = *(const half8*)(ldsraw + (par) * 32768 + lrow * 512 +      \
                      (((kq + 4 * ks) ^ sw) * 16));                           \
        half8 a1 = *(const half8*)(ldsraw + (par) * 32768 +                   \
                      (lrow + 16) * 512 + (((kq + 4 * ks) ^ sw) * 16));       \
        acc0 = __builtin_amdgcn_mfma_f32_16x16x32_f16(a0, (BW)[(CO) + ks],    \
                                                      acc0, 0, 0, 0);         \
        acc1 = __builtin_amdgcn_mfma_f32_16x16x32_f16(a1, (BW)[(CO) + ks],    \
                                                      acc1, 0, 0, 0);         \
    } } while (0)

// chunk order: h0 (k512-767, BW[16..23]), h1 (k768-1023, BW[24..31]),
//              x0 (k0-255,   BW[0..7]),   x1 (k256-511,  BW[8..15])
// h-chunks prefetched BEFORE the flag poll (their producer flag was polled one
// phase earlier => data complete; addresses write-once => caches never stale).
#define PHASE(PH, WAIT, XSRC, HSRC, BW, BZ, CREG, HREG, HDST) do {            \
    const char* bx = (const char*)(XSRC) + (size_t)m0 * 1024;                 \
    const char* bh = (const char*)(HSRC) + (size_t)m0 * 1024;                 \
    i32x4 tmp[16];                                                            \
    ISSUE_CHUNK(bh, 0, 0);                                                    \
    ISSUE_CHUNK(bh, 1, 8);                                                    \
    if ((WAIT) && tid == 0) {                                                 \
        unsigned* fb = flags + (((PH) - 1) * 4 + m) * 256;                    \
        for (;;) {                                                            \
            unsigned s = 0;                                                   \
            _Pragma("unroll")                                                 \
            for (int o = 0; o < 8; ++o)                                       \
                s += __hip_atomic_load(fb + o * 32, __ATOMIC_RELAXED,         \
                                       __HIP_MEMORY_SCOPE_SYSTEM);            \
            if (s == 64u) break;                                              \
            __builtin_amdgcn_s_sleep(1);                                      \
        }                                                                     \
    }                                                                         \
    __syncthreads();                                                          \
    f32x4 acc0 = {0.f,0.f,0.f,0.f}, acc1 = {0.f,0.f,0.f,0.f};                 \
    WRITE_CHUNK(0, 0, 15);                                                    \
    __syncthreads();                                                          \
    ISSUE_CHUNK(bx, 0, 0);                                                    \
    MFMA_CHUNK(0, 16, BW);                                                    \
    WRITE_CHUNK(1, 8, 15);                                                    \
    __syncthreads();                                                          \
    ISSUE_CHUNK(bx, 1, 8);                                                    \
    MFMA_CHUNK(1, 24, BW);                                                    \
    WRITE_CHUNK(0, 0, 15);                                                    \
    __syncthreads();                                                          \
    MFMA_CHUNK(0, 0, BW);                                                     \
    WRITE_CHUNK(1, 8, 7);                                                     \
    __syncthreads();                                                          \
    MFMA_CHUNK(1, 8, BW);                                                     \
    /* ---- epilogue: transpose, cell, LDS-gather, coalesced 16B flush ---- */ \
    float* scrw = (float*)(ldsraw + w * 1024);                                \
    h16* hbuf = (h16*)(ldsraw + 8192);                                        \
    _Pragma("unroll")                                                         \
    for (int mt = 0; mt < 2; ++mt) {                                          \
        f32x4 accv = mt ? acc1 : acc0;                                        \
        _Pragma("unroll")                                                     \
        for (int rr = 0; rr < 4; ++rr)                                        \
            scrw[(kq * 4 + rr) * 16 + mcol] = accv[rr];                       \
        float4 g4 = *(const float4*)&scrw[(lane >> 2) * 16 + (lane & 3) * 4]; \
        float iv = sigf(g4.x + (BZ).x);                                       \
        float fv = sigf(g4.y + (BZ).y);                                       \
        float gv = tanhf_(g4.z + (BZ).z);                                     \
        float ov = sigf(g4.w + (BZ).w);                                       \
        float cc = fv * (CREG)[mt] + iv * gv;                                 \
        float hh = ov * tanhf_(cc);                                           \
        (CREG)[mt] = cc; (HREG)[mt] = hh;                                     \
        hbuf[(lrloc + mt * 16) * 8 + luloc] = (h16)hh;                        \
    }                                                                         \
    __syncthreads();                                                          \
    if (tid < 64) {                                                           \
        i32x4 hv16 = *(const i32x4*)(ldsraw + 8192 + tid * 16);               \
        int voff = (m0 + tid) * 1024 + u0 * 2;                                \
        asm volatile("global_store_dwordx4 %0, %1, %2 sc0 sc1"                \
            :: "v"(voff), "v"(hv16), "s"(HDST) : "memory");                   \
    }                                                                         \
    asm volatile("s_waitcnt vmcnt(0)" ::: "memory");                          \
    __syncthreads();                                                          \
    if (tid == 0)                                                             \
        __hip_atomic_fetch_add(flags + (((PH) * 4 + m) * 8 + myoct) * 32, 1u, \
                               __ATOMIC_RELAXED, __HIP_MEMORY_SCOPE_AGENT);   \
} while (0)

#pragma unroll 1
    for (int t = 0; t < TT; ++t) {
        const h16* x0src = t ? (H1 + (size_t)(t - 1) * 131072) : Xinit;
        const h16* h0src = t ? (H0 + (size_t)(t - 1) * 131072) : H0init;
        // layer 0 (phase 2t): A = [x0src | h0src] -> H0[t]
        PHASE(2 * t, t > 0, x0src, h0src, Bw0, bz0, creg[0], hreg[0],
              (H0 + (size_t)t * 131072));
        const h16* h1src = t ? (H1 + (size_t)(t - 1) * 131072) : H1init;
        // layer 1 (phase 2t+1): A = [H0[t] | h1src] -> H1[t]
        PHASE(2 * t + 1, 1, (H0 + (size_t)t * 131072), h1src, Bw1, bz1,
              creg[1], hreg[1], (H1 + (size_t)t * 131072));
    }

    // ---- final hT / cT (normal stores; kernel-end release flushes) ----
#pragma unroll
    for (int mt = 0; mt < 2; ++mt) {
        int idx = (erow0 + mt * 16) * 512 + eunit;
        h_st[idx]          = hreg[0][mt];
        h_st[131072 + idx] = hreg[1][mt];
        c_st[idx]          = creg[0][mt];
        c_st[131072 + idx] = creg[1][mt];
    }
}

// ---------------- final FC over all stored h1(t): (T*B) x 7, K=512 -----------
__global__ __launch_bounds__(256) void fc_kernel(
    const h16* __restrict__ H1, const float* __restrict__ Wfc,
    const float* __restrict__ bfc, float* __restrict__ out)
{
    __shared__ float wl[NO * 512];
    for (int i = threadIdx.x; i < NO * 512; i += 256) wl[i] = Wfc[i];
    __syncthreads();
    const int wave = threadIdx.x >> 6, lane = threadIdx.x & 63;
    const int row = blockIdx.x * 4 + wave;   // row = t*256 + b
    const h16* hr = H1 + (size_t)row * 512;
    float acc[NO] = {0, 0, 0, 0, 0, 0, 0};
#pragma unroll
    for (int i = 0; i < 8; ++i) {
        float hv = (float)hr[i * 64 + lane];
#pragma unroll
        for (int o = 0; o < NO; ++o) acc[o] += hv * wl[o * 512 + i * 64 + lane];
    }
#pragma unroll
    for (int o = 0; o < NO; ++o)
#pragma unroll
        for (int off = 32; off; off >>= 1) acc[o] += __shfl_down(acc[o], off);
    if (lane == 0) {
        const int t = row >> 8, b = row & 255;
#pragma unroll
        for (int o = 0; o < NO; ++o) out[b * (TT * NO) + t * NO + o] = acc[o] + bfc[o];
    }
}

extern "C" void kernel_launch(void* const* d_in, const int* in_sizes, int n_in,
                              void* d_out, int out_size, void* d_ws, size_t ws_size,
                              hipStream_t stream)
{
    (void)in_sizes; (void)n_in; (void)out_size; (void)ws_size;
    const float* x   = (const float*)d_in[0];
    const float* h0  = (const float*)d_in[1];
    const float* c0  = (const float*)d_in[2];
    const float* Wih = (const float*)d_in[3];
    const float* Whh = (const float*)d_in[4];
    const float* bih = (const float*)d_in[5];
    const float* bhh = (const float*)d_in[6];
    const float* Wfc = (const float*)d_in[7];
    const float* bfc = (const float*)d_in[8];

    float* outf = (float*)d_out;                 // decoded (256*64*7)
    float* h_st = outf + 114688;                 // hT (2,256,512)
    float* c_st = h_st + 262144;                 // cT (2,256,512)

    char* ws = (char*)d_ws;
    float*    bias   = (float*)(ws + 8388608);           // 16 KB
    h16*      Xinit  = (h16*)(ws + 8404992);             // 256 KB
    h16*      H0init = (h16*)(ws + 8667136);             // 256 KB
    h16*      H1init = (h16*)(ws + 8929280);             // 256 KB
    h16*      H0     = (h16*)(ws + 9191424);             // 16 MB (64 steps)
    h16*      H1     = (h16*)(ws + 25968640);            // 16 MB (64 steps)
    unsigned* flags  = (unsigned*)(ws + 42745856);       // 512 KB

    prologue<<<1680, 256, 0, stream>>>(x, h0, bih, bhh,
                                       Xinit, H0init, H1init, bias, flags);
    lstm_persist<<<256, 256, 0, stream>>>(Wih, Whh, bias, c0,
                                          Xinit, H0init, H1init,
                                          H0, H1, h_st, c_st, flags);
    fc_kernel<<<4096, 256, 0, stream>>>(H1, Wfc, bfc, outf);
}